// Round 3
// baseline (1668.504 us; speedup 1.0000x reference)
//
#include <hip/hip_runtime.h>
#include <stdint.h>

// Problem constants
#define BN_TOTAL 65536      // B*N = 16*4096 rows
#define DDIM 256            // D
#define KCLUST 4096         // K
#define DECAY 0.99f
#define OMD 0.01f           // 1 - DECAY
#define EPSC 1e-5f

// Output layout (float offsets into d_out), reference tuple order
#define OFF_ZQ   0
#define OFF_IDX  16777216
#define OFF_LOSS 16842752
#define OFF_NE   16842753
#define OFF_NCS  17891329
#define OFF_NEA  17895425

// ws layout (byte offsets):
//  0        loss accumulator (double, zeroed)
//  8        tot (float)
//  64       hist int[4096]   (zeroed)           -> 16448
//  16448    offs int[4096]                      -> 32832
//  32832    enorm f32[4096]                     -> 49216
//  49216    bidx u16[65536]                     -> 180288
//  180288   best u64[65536] (memset 0xFF); sorted u16[65536] overlays after K1b
//  704576   eh fp16[4096*256]                   -> 2801728
//  2801728  el fp16[4096*256] (scaled x4096)    -> 4898880
#define WSB_HIST  64
#define WSB_OFFS  16448
#define WSB_ENORM 32832
#define WSB_BIDX  49216
#define WSB_BEST  180288
#define WSB_EH    704576
#define WSB_EL    2801728

typedef _Float16 half8 __attribute__((ext_vector_type(8)));
typedef _Float16 half4 __attribute__((ext_vector_type(4)));
typedef float f32x4 __attribute__((ext_vector_type(4)));

#define MFMA16x32(a, b, c) __builtin_amdgcn_mfma_f32_16x16x32_f16(a, b, c, 0, 0, 0)

__device__ __forceinline__ void gload16(const void* gsrc, void* ldst) {
  __builtin_amdgcn_global_load_lds(
      (const __attribute__((address_space(1))) uint32_t*)(uintptr_t)gsrc,
      (__attribute__((address_space(3))) uint32_t*)(uint32_t)(uintptr_t)ldst,
      16, 0, 0);
}

__device__ __forceinline__ unsigned int fkey(float f) {
  unsigned int u = __float_as_uint(f);
  return (u & 0x80000000u) ? ~u : (u | 0x80000000u);
}

// ---------------- K0: split embed -> fp16 hi/lo (+ row norms) ----------------
__global__ __launch_bounds__(256) void presplit_embed(
    const float* __restrict__ embed, _Float16* __restrict__ eh,
    _Float16* __restrict__ el, float* __restrict__ enorm) {
  const int w = threadIdx.x >> 6;
  const int l = threadIdx.x & 63;
  const int row = blockIdx.x * 4 + w;
  const f32x4 v = *reinterpret_cast<const f32x4*>(embed + (size_t)row * DDIM + l * 4);
  half4 h, lo;
  float s = 0.0f;
  #pragma unroll
  for (int j = 0; j < 4; ++j) {
    const float x = v[j];
    s += x * x;
    const _Float16 hh = (_Float16)x;
    h[j] = hh;
    lo[j] = (_Float16)((x - (float)hh) * 4096.0f);
  }
  *reinterpret_cast<half4*>(eh + (size_t)row * DDIM + l * 4) = h;
  *reinterpret_cast<half4*>(el + (size_t)row * DDIM + l * 4) = lo;
  #pragma unroll
  for (int off = 32; off; off >>= 1) s += __shfl_xor(s, off, 64);
  if (l == 0) enorm[row] = s;
}

// ---------------- K1: MFMA distance + argmin (split-N for occupancy) --------
// grid (512, 2): x tiles 128 m-rows, y picks a 2048-cluster half. Per-row
// winner of each half merged via atomicMin on (fkey(score)<<32 | idx).
__global__ __launch_bounds__(256, 4) void dist_argmin(
    const float* __restrict__ z, const _Float16* __restrict__ eh,
    const _Float16* __restrict__ el, const float* __restrict__ enorm,
    unsigned long long* __restrict__ best) {
  __shared__ _Float16 lbuf[2][8192];  // [buf][hi 4096 | lo 4096] halfs
  const int t = threadIdx.x;
  const int w = t >> 6;
  const int l = t & 63;
  const int lg = l >> 4;   // 0..3
  const int lr = l & 15;   // A-row / B-col / D-col
  const int m0 = blockIdx.x * 128 + w * 32;
  const int nbase = blockIdx.y * (KCLUST / 2);
  const int tbase = nbase >> 4;  // first 16-col tile index

  // ---- load z A-fragments, split f32 -> fp16 hi + scaled lo ----
  half8 ah[2][8], al[2][8];
  #pragma unroll
  for (int rg = 0; rg < 2; ++rg) {
    #pragma unroll
    for (int kf = 0; kf < 8; ++kf) {
      const float* zp = z + (size_t)(m0 + rg * 16 + lr) * DDIM + kf * 32 + lg * 8;
      const f32x4 z0 = *reinterpret_cast<const f32x4*>(zp);
      const f32x4 z1 = *reinterpret_cast<const f32x4*>(zp + 4);
      #pragma unroll
      for (int j = 0; j < 4; ++j) {
        const _Float16 h0 = (_Float16)z0[j];
        ah[rg][kf][j] = h0;
        al[rg][kf][j] = (_Float16)((z0[j] - (float)h0) * 4096.0f);
        const _Float16 h1 = (_Float16)z1[j];
        ah[rg][kf][j + 4] = h1;
        al[rg][kf][j + 4] = (_Float16)((z1[j] - (float)h1) * 4096.0f);
      }
    }
  }

  // staging src offsets (XOR swizzle folded into GLOBAL address; LDS linear)
  int srcoff[2];
  #pragma unroll
  for (int c01 = 0; c01 < 2; ++c01) {
    const int q = c01 * 4096 + t * 16;
    const int row = q >> 9;
    const int cc = q & 511;
    srcoff[c01] = row * 512 + (cc ^ ((row & 7) << 4));
  }
  const char* ehb = (const char*)eh;
  const char* elb = (const char*)el;

#define STAGE(nt, bb)                                                   \
  {                                                                     \
    const int nb_ = (tbase + (nt)) * 8192;                              \
    char* d_ = (char*)&lbuf[bb][0];                                     \
    gload16(ehb + nb_ + srcoff[0], d_ + t * 16);                        \
    gload16(ehb + nb_ + srcoff[1], d_ + 4096 + t * 16);                 \
    gload16(elb + nb_ + srcoff[0], d_ + 8192 + t * 16);                 \
    gload16(elb + nb_ + srcoff[1], d_ + 12288 + t * 16);                \
  }

  float minv[2][4];
  int mini[2][4];
  #pragma unroll
  for (int rg = 0; rg < 2; ++rg)
    #pragma unroll
    for (int r = 0; r < 4; ++r) { minv[rg][r] = 3.4e38f; mini[rg][r] = 0; }

  STAGE(0, 0);
  float en_cur = enorm[nbase + lr];

  for (int nt = 0; nt < 128; ++nt) {
    __syncthreads();  // vmcnt(0) drained before barrier -> buf[nt&1] ready
    if (nt + 1 < 128) STAGE(nt + 1, (nt + 1) & 1);
    const float en_next = (nt + 1 < 128) ? enorm[nbase + (nt + 1) * 16 + lr] : 0.0f;

    const char* bb = (const char*)&lbuf[nt & 1][0];
    f32x4 acc_h[2], acc_xa[2], acc_xb[2];
    #pragma unroll
    for (int rg = 0; rg < 2; ++rg) {
      acc_h[rg] = f32x4{0.f, 0.f, 0.f, 0.f};
      acc_xa[rg] = f32x4{0.f, 0.f, 0.f, 0.f};
      acc_xb[rg] = f32x4{0.f, 0.f, 0.f, 0.f};
    }
    const int swv = (lr & 7) << 4;
    #pragma unroll
    for (int kf = 0; kf < 8; ++kf) {
      const int ro = lr * 512 + ((kf * 64 + lg * 16) ^ swv);
      const half8 bh = *reinterpret_cast<const half8*>(bb + ro);
      const half8 bl = *reinterpret_cast<const half8*>(bb + 8192 + ro);
      acc_h[0] = MFMA16x32(ah[0][kf], bh, acc_h[0]);
      acc_h[1] = MFMA16x32(ah[1][kf], bh, acc_h[1]);
      acc_xa[0] = MFMA16x32(al[0][kf], bh, acc_xa[0]);
      acc_xa[1] = MFMA16x32(al[1][kf], bh, acc_xa[1]);
      acc_xb[0] = MFMA16x32(ah[0][kf], bl, acc_xb[0]);
      acc_xb[1] = MFMA16x32(ah[1][kf], bl, acc_xb[1]);
    }
    const int n = nbase + nt * 16 + lr;
    #pragma unroll
    for (int rg = 0; rg < 2; ++rg) {
      #pragma unroll
      for (int r = 0; r < 4; ++r) {
        const float s = fmaf(-2.0f, acc_h[rg][r],
                        fmaf(-2.0f / 4096.0f, acc_xa[rg][r] + acc_xb[rg][r], en_cur));
        if (s < minv[rg][r]) { minv[rg][r] = s; mini[rg][r] = n; }
      }
    }
    en_cur = en_next;
  }
#undef STAGE

  // reduce across 16 lr lanes (different cols of the same row)
  #pragma unroll
  for (int mask = 1; mask < 16; mask <<= 1) {
    #pragma unroll
    for (int rg = 0; rg < 2; ++rg) {
      #pragma unroll
      for (int r = 0; r < 4; ++r) {
        const float ov = __shfl_xor(minv[rg][r], mask, 64);
        const int oi = __shfl_xor(mini[rg][r], mask, 64);
        if (ov < minv[rg][r] || (ov == minv[rg][r] && oi < mini[rg][r])) {
          minv[rg][r] = ov;
          mini[rg][r] = oi;
        }
      }
    }
  }
  if (lr == 0) {
    #pragma unroll
    for (int rg = 0; rg < 2; ++rg) {
      #pragma unroll
      for (int r = 0; r < 4; ++r) {
        const int row = m0 + rg * 16 + lg * 4 + r;  // D row = (l>>4)*4 + r
        const unsigned long long pk =
            ((unsigned long long)fkey(minv[rg][r]) << 32) | (unsigned int)mini[rg][r];
        atomicMin(&best[row], pk);
      }
    }
  }
}

// ---------------- K1b: extract winners, histogram ----------------
__global__ __launch_bounds__(256) void extract_hist(
    const unsigned long long* __restrict__ best, unsigned short* __restrict__ bidx,
    float* __restrict__ idx_out, int* __restrict__ hist) {
  const int row = blockIdx.x * 256 + threadIdx.x;
  const int k = (int)(best[row] & 0xffffffffULL);
  bidx[row] = (unsigned short)k;
  idx_out[row] = (float)k;
  atomicAdd(&hist[k], 1);
}

// ---------------- K2: gather z_q + loss (pure BW, no scatter) ----------------
__global__ __launch_bounds__(256) void zq_loss(
    const float* __restrict__ z, const float* __restrict__ embed,
    const unsigned short* __restrict__ bidx, float* __restrict__ out,
    double* __restrict__ loss_acc) {
  const int w = threadIdx.x >> 6;
  const int lane = threadIdx.x & 63;
  const int base = blockIdx.x * 16 + w * 4;
  float lsum = 0.0f;
  #pragma unroll
  for (int rr = 0; rr < 4; ++rr) {
    const int row = base + rr;
    const int k = (int)bidx[row];
    const float4 zv = *reinterpret_cast<const float4*>(z + (size_t)row * DDIM + lane * 4);
    const float4 ev = *reinterpret_cast<const float4*>(embed + (size_t)k * DDIM + lane * 4);
    float4 zq;
    zq.x = zv.x + (ev.x - zv.x);
    zq.y = zv.y + (ev.y - zv.y);
    zq.z = zv.z + (ev.z - zv.z);
    zq.w = zv.w + (ev.w - zv.w);
    *reinterpret_cast<float4*>(out + OFF_ZQ + (size_t)row * DDIM + lane * 4) = zq;
    const float dx = ev.x - zv.x, dy = ev.y - zv.y, dz = ev.z - zv.z, dw = ev.w - zv.w;
    lsum += dx * dx + dy * dy + dz * dz + dw * dw;
  }
  #pragma unroll
  for (int off = 32; off; off >>= 1) lsum += __shfl_xor(lsum, off, 64);
  if (lane == 0) atomicAdd(loss_acc, (double)lsum);
}

// ---------------- K3: prefix scan of hist + new_cluster_size + tot + loss ----
__global__ __launch_bounds__(1024) void prefix_ncs(
    const float* __restrict__ cluster_size, const int* __restrict__ hist,
    int* __restrict__ offs, float* __restrict__ out,
    const double* __restrict__ loss_acc, float* __restrict__ tot_p) {
  __shared__ int wpart[16];
  __shared__ float fpart[16];
  const int t = threadIdx.x;
  const int lane = t & 63;
  const int wid = t >> 6;
  const int k0 = t * 4;
  int h[4];
  #pragma unroll
  for (int i = 0; i < 4; ++i) h[i] = hist[k0 + i];
  const int s = h[0] + h[1] + h[2] + h[3];
  int incl = s;
  #pragma unroll
  for (int off = 1; off < 64; off <<= 1) {
    const int v = __shfl_up(incl, off, 64);
    if (lane >= off) incl += v;
  }
  if (lane == 63) wpart[wid] = incl;
  float totl = 0.0f;
  #pragma unroll
  for (int i = 0; i < 4; ++i) {
    const float ncs = cluster_size[k0 + i] * DECAY + OMD * (float)h[i];
    out[OFF_NCS + k0 + i] = ncs;
    totl += ncs;
  }
  #pragma unroll
  for (int off = 32; off; off >>= 1) totl += __shfl_xor(totl, off, 64);
  if (lane == 0) fpart[wid] = totl;
  __syncthreads();
  int base = 0;
  for (int i = 0; i < wid; ++i) base += wpart[i];
  const int excl = base + incl - s;
  offs[k0] = excl;
  offs[k0 + 1] = excl + h[0];
  offs[k0 + 2] = excl + h[0] + h[1];
  offs[k0 + 3] = excl + h[0] + h[1] + h[2];
  if (t == 0) {
    float tt = 0.0f;
    #pragma unroll
    for (int i = 0; i < 16; ++i) tt += fpart[i];
    tot_p[0] = tt;
    out[OFF_LOSS] = (float)(2.0 * loss_acc[0] / 16777216.0);
  }
}

// ---------------- K4: scatter row ids into cluster-sorted order --------------
__global__ __launch_bounds__(256) void scatter_rows(
    const unsigned short* __restrict__ bidx, int* __restrict__ offs,
    unsigned short* __restrict__ sorted) {
  const int row = blockIdx.x * 256 + threadIdx.x;
  const int k = (int)bidx[row];
  const int pos = atomicAdd(&offs[k], 1);
  sorted[pos] = (unsigned short)row;
}

// ---------------- K5: per-cluster sum of z rows (raw es) ---------------------
__global__ __launch_bounds__(64) void cluster_sum(
    const float* __restrict__ z, const unsigned short* __restrict__ sorted,
    const int* __restrict__ hist, const int* __restrict__ offs,
    float* __restrict__ out) {
  const int c = blockIdx.x;
  const int lane = threadIdx.x;
  const int cnt = hist[c];
  const int start = offs[c] - cnt;  // offs became end-pointers after K4
  f32x4 acc = f32x4{0.f, 0.f, 0.f, 0.f};
  for (int b = 0; b < cnt; b += 64) {
    const int nn = min(64, cnt - b);
    const int myrow = (lane < nn) ? (int)sorted[start + b + lane] : 0;
    for (int j = 0; j < nn; ++j) {
      const int row = __shfl(myrow, j, 64);
      acc += *reinterpret_cast<const f32x4*>(z + (size_t)row * DDIM + lane * 4);
    }
  }
  *reinterpret_cast<f32x4*>(out + OFF_NEA + (size_t)c * DDIM + lane * 4) = acc;
}

// ---------------- K6: new_embed_avg (in place) + new_embed -------------------
__global__ __launch_bounds__(256) void finalize_embed(
    const float* __restrict__ embed_avg, float* __restrict__ out,
    const float* __restrict__ tot_p) {
  const int e = blockIdx.x * 256 + threadIdx.x;
  const int k = e >> 8;
  const float tot = tot_p[0];
  const float es = out[OFF_NEA + e];
  const float nea = embed_avg[e] * DECAY + OMD * es;
  const float ncs = out[OFF_NCS + k];
  const float csn = (ncs + EPSC) / (tot + (float)KCLUST * EPSC) * tot;
  out[OFF_NEA + e] = nea;
  out[OFF_NE + e] = nea / csn;
}

extern "C" void kernel_launch(void* const* d_in, const int* in_sizes, int n_in,
                              void* d_out, int out_size, void* d_ws, size_t ws_size,
                              hipStream_t stream) {
  const float* z = (const float*)d_in[0];
  const float* embed = (const float*)d_in[1];
  const float* cluster_size = (const float*)d_in[2];
  const float* embed_avg = (const float*)d_in[3];
  float* out = (float*)d_out;
  char* wsb = (char*)d_ws;
  double* loss_acc = (double*)wsb;
  float* tot_p = (float*)(wsb + 8);
  int* hist = (int*)(wsb + WSB_HIST);
  int* offs = (int*)(wsb + WSB_OFFS);
  float* enorm = (float*)(wsb + WSB_ENORM);
  unsigned short* bidx = (unsigned short*)(wsb + WSB_BIDX);
  unsigned long long* best = (unsigned long long*)(wsb + WSB_BEST);
  unsigned short* sorted = (unsigned short*)(wsb + WSB_BEST);  // overlays best
  _Float16* eh = (_Float16*)(wsb + WSB_EH);
  _Float16* el = (_Float16*)(wsb + WSB_EL);

  // zero loss+hist header region; set best keys to +inf
  hipMemsetAsync(wsb, 0, 16448, stream);
  hipMemsetAsync(best, 0xFF, (size_t)BN_TOTAL * 8, stream);

  presplit_embed<<<KCLUST / 4, 256, 0, stream>>>(embed, eh, el, enorm);
  dist_argmin<<<dim3(BN_TOTAL / 128, 2), 256, 0, stream>>>(z, eh, el, enorm, best);
  extract_hist<<<BN_TOTAL / 256, 256, 0, stream>>>(best, bidx, out + OFF_IDX, hist);
  zq_loss<<<BN_TOTAL / 16, 256, 0, stream>>>(z, embed, bidx, out, loss_acc);
  prefix_ncs<<<1, 1024, 0, stream>>>(cluster_size, hist, offs, out, loss_acc, tot_p);
  scatter_rows<<<BN_TOTAL / 256, 256, 0, stream>>>(bidx, offs, sorted);
  cluster_sum<<<KCLUST, 64, 0, stream>>>(z, sorted, hist, offs, out);
  finalize_embed<<<KCLUST, 256, 0, stream>>>(embed_avg, out, tot_p);
}

// Round 5
// 701.522 us; speedup vs baseline: 2.3784x; 2.3784x over previous
//
#include <hip/hip_runtime.h>
#include <stdint.h>

// Problem constants
#define BN_TOTAL 65536      // B*N = 16*4096 rows
#define DDIM 256            // D
#define KCLUST 4096         // K
#define DECAY 0.99f
#define OMD 0.01f           // 1 - DECAY
#define EPSC 1e-5f

// Output layout (float offsets into d_out), reference tuple order
#define OFF_ZQ   0
#define OFF_IDX  16777216
#define OFF_LOSS 16842752
#define OFF_NE   16842753
#define OFF_NCS  17891329
#define OFF_NEA  17895425

// ws layout (byte offsets):
//  0        loss accumulator (double, zeroed)
//  8        tot (float)
//  64       hist int[4096]   (zeroed)           -> 16448
//  16448    offs int[4096]                      -> 32832
//  32832    enorm f32[4096]                     -> 49216
//  49216    bidx u16[65536]                     -> 180288
//  180288   best u64[65536] (memset 0xFF); sorted u16[65536] overlays after use
//  704576   eh fp16[4096*256]
//  2801728  el fp16[4096*256] (scaled x4096)
#define WSB_HIST  64
#define WSB_OFFS  16448
#define WSB_ENORM 32832
#define WSB_BIDX  49216
#define WSB_BEST  180288
#define WSB_EH    704576
#define WSB_EL    2801728

typedef _Float16 half8 __attribute__((ext_vector_type(8)));
typedef _Float16 half4 __attribute__((ext_vector_type(4)));
typedef float f32x4 __attribute__((ext_vector_type(4)));

#define MFMA16x32(a, b, c) __builtin_amdgcn_mfma_f32_16x16x32_f16(a, b, c, 0, 0, 0)

__device__ __forceinline__ void gload16(const void* gsrc, void* ldst) {
  __builtin_amdgcn_global_load_lds(
      (const __attribute__((address_space(1))) uint32_t*)(uintptr_t)gsrc,
      (__attribute__((address_space(3))) uint32_t*)(uint32_t)(uintptr_t)ldst,
      16, 0, 0);
}

__device__ __forceinline__ unsigned int fkey(float f) {
  unsigned int u = __float_as_uint(f);
  return (u & 0x80000000u) ? ~u : (u | 0x80000000u);
}

// ---------------- K0: split embed -> fp16 hi/lo (+ row norms) ----------------
__global__ __launch_bounds__(256) void presplit_embed(
    const float* __restrict__ embed, _Float16* __restrict__ eh,
    _Float16* __restrict__ el, float* __restrict__ enorm) {
  const int w = threadIdx.x >> 6;
  const int l = threadIdx.x & 63;
  const int row = blockIdx.x * 4 + w;
  const f32x4 v = *reinterpret_cast<const f32x4*>(embed + (size_t)row * DDIM + l * 4);
  half4 h, lo;
  float s = 0.0f;
  #pragma unroll
  for (int j = 0; j < 4; ++j) {
    const float x = v[j];
    s += x * x;
    const _Float16 hh = (_Float16)x;
    h[j] = hh;
    lo[j] = (_Float16)((x - (float)hh) * 4096.0f);
  }
  *reinterpret_cast<half4*>(eh + (size_t)row * DDIM + l * 4) = h;
  *reinterpret_cast<half4*>(el + (size_t)row * DDIM + l * 4) = lo;
  #pragma unroll
  for (int off = 32; off; off >>= 1) s += __shfl_xor(s, off, 64);
  if (l == 0) enorm[row] = s;
}

// ---------------- K1: MFMA distance + argmin ----------------
// 512 threads = 8 waves x 32 m-rows = 256 rows/block. NO waves-per-EU hint:
// natural VGPR ~112 -> 4 waves/SIMD -> 2 blocks/CU (r3's forced-occupancy
// spill disaster avoided). grid (256, 2): y picks a 2048-cluster half;
// halves merged via atomicMin on (fkey(score)<<32 | idx).
__global__ __launch_bounds__(512) void dist_argmin(
    const float* __restrict__ z, const _Float16* __restrict__ eh,
    const _Float16* __restrict__ el, const float* __restrict__ enorm,
    unsigned long long* __restrict__ best) {
  __shared__ _Float16 lbuf[2][8192];  // [buf][hi 8KB | lo 8KB]
  const int t = threadIdx.x;
  const int w = t >> 6;
  const int l = t & 63;
  const int lg = l >> 4;   // 0..3
  const int lr = l & 15;   // A-row / B-col / D-col
  const int m0 = blockIdx.x * 256 + w * 32;
  const int nbase = blockIdx.y * (KCLUST / 2);
  const int tbase = nbase >> 4;

  // ---- load z A-fragments, split f32 -> fp16 hi + scaled lo ----
  half8 ah[2][8], al[2][8];
  #pragma unroll
  for (int rg = 0; rg < 2; ++rg) {
    #pragma unroll
    for (int kf = 0; kf < 8; ++kf) {
      const float* zp = z + (size_t)(m0 + rg * 16 + lr) * DDIM + kf * 32 + lg * 8;
      const f32x4 z0 = *reinterpret_cast<const f32x4*>(zp);
      const f32x4 z1 = *reinterpret_cast<const f32x4*>(zp + 4);
      #pragma unroll
      for (int j = 0; j < 4; ++j) {
        const _Float16 h0 = (_Float16)z0[j];
        ah[rg][kf][j] = h0;
        al[rg][kf][j] = (_Float16)((z0[j] - (float)h0) * 4096.0f);
        const _Float16 h1 = (_Float16)z1[j];
        ah[rg][kf][j + 4] = h1;
        al[rg][kf][j + 4] = (_Float16)((z1[j] - (float)h1) * 4096.0f);
      }
    }
  }

  // staging src offset (XOR swizzle folded into GLOBAL address; LDS linear)
  // 512 threads x 16B = 8KB = one hi tile; lo via second gload to +8192.
  const int q = t * 16;
  const int srow = q >> 9;
  const int scc = q & 511;
  const int srcoff = srow * 512 + (scc ^ ((srow & 7) << 4));
  const char* ehb = (const char*)eh;
  const char* elb = (const char*)el;

#define STAGE(nt, bb)                                  \
  {                                                    \
    const int nb_ = (tbase + (nt)) * 8192;             \
    char* d_ = (char*)&lbuf[bb][0];                    \
    gload16(ehb + nb_ + srcoff, d_ + t * 16);          \
    gload16(elb + nb_ + srcoff, d_ + 8192 + t * 16);   \
  }

  float minv[2][4];
  int mini[2][4];
  #pragma unroll
  for (int rg = 0; rg < 2; ++rg)
    #pragma unroll
    for (int r = 0; r < 4; ++r) { minv[rg][r] = 3.4e38f; mini[rg][r] = 0; }

  STAGE(0, 0);
  float en_cur = enorm[nbase + lr];

  for (int nt = 0; nt < 128; ++nt) {
    __syncthreads();  // drains vmcnt(0) -> buf[nt&1] ready
    if (nt + 1 < 128) STAGE(nt + 1, (nt + 1) & 1);
    const float en_next = (nt + 1 < 128) ? enorm[nbase + (nt + 1) * 16 + lr] : 0.0f;

    const char* bb = (const char*)&lbuf[nt & 1][0];
    f32x4 acc_h[2], acc_xa[2], acc_xb[2];
    #pragma unroll
    for (int rg = 0; rg < 2; ++rg) {
      acc_h[rg] = f32x4{0.f, 0.f, 0.f, 0.f};
      acc_xa[rg] = f32x4{0.f, 0.f, 0.f, 0.f};
      acc_xb[rg] = f32x4{0.f, 0.f, 0.f, 0.f};
    }
    const int swv = (lr & 7) << 4;
    #pragma unroll
    for (int kf = 0; kf < 8; ++kf) {
      const int ro = lr * 512 + ((kf * 64 + lg * 16) ^ swv);
      const half8 bh = *reinterpret_cast<const half8*>(bb + ro);
      const half8 bl = *reinterpret_cast<const half8*>(bb + 8192 + ro);
      acc_h[0] = MFMA16x32(ah[0][kf], bh, acc_h[0]);
      acc_h[1] = MFMA16x32(ah[1][kf], bh, acc_h[1]);
      acc_xa[0] = MFMA16x32(al[0][kf], bh, acc_xa[0]);
      acc_xa[1] = MFMA16x32(al[1][kf], bh, acc_xa[1]);
      acc_xb[0] = MFMA16x32(ah[0][kf], bl, acc_xb[0]);
      acc_xb[1] = MFMA16x32(ah[1][kf], bl, acc_xb[1]);
    }
    const int n = nbase + nt * 16 + lr;
    #pragma unroll
    for (int rg = 0; rg < 2; ++rg) {
      #pragma unroll
      for (int r = 0; r < 4; ++r) {
        const float s = fmaf(-2.0f, acc_h[rg][r],
                        fmaf(-2.0f / 4096.0f, acc_xa[rg][r] + acc_xb[rg][r], en_cur));
        if (s < minv[rg][r]) { minv[rg][r] = s; mini[rg][r] = n; }
      }
    }
    en_cur = en_next;
  }
#undef STAGE

  // reduce across 16 lr lanes (different cols of the same row)
  #pragma unroll
  for (int mask = 1; mask < 16; mask <<= 1) {
    #pragma unroll
    for (int rg = 0; rg < 2; ++rg) {
      #pragma unroll
      for (int r = 0; r < 4; ++r) {
        const float ov = __shfl_xor(minv[rg][r], mask, 64);
        const int oi = __shfl_xor(mini[rg][r], mask, 64);
        if (ov < minv[rg][r] || (ov == minv[rg][r] && oi < mini[rg][r])) {
          minv[rg][r] = ov;
          mini[rg][r] = oi;
        }
      }
    }
  }
  if (lr == 0) {
    #pragma unroll
    for (int rg = 0; rg < 2; ++rg) {
      #pragma unroll
      for (int r = 0; r < 4; ++r) {
        const int row = m0 + rg * 16 + lg * 4 + r;  // D row = (l>>4)*4 + r
        const unsigned long long pk =
            ((unsigned long long)fkey(minv[rg][r]) << 32) | (unsigned int)mini[rg][r];
        atomicMin(&best[row], pk);
      }
    }
  }
}

// ---------------- K2: extract + hist + z_q gather + loss (fused) -------------
__global__ __launch_bounds__(256) void post_assign(
    const float* __restrict__ z, const float* __restrict__ embed,
    const unsigned long long* __restrict__ best, unsigned short* __restrict__ bidx,
    float* __restrict__ out, int* __restrict__ hist,
    double* __restrict__ loss_acc) {
  const int w = threadIdx.x >> 6;
  const int lane = threadIdx.x & 63;
  const int base = blockIdx.x * 16 + w * 4;
  float lsum = 0.0f;
  #pragma unroll
  for (int rr = 0; rr < 4; ++rr) {
    const int row = base + rr;
    const int k = (int)(best[row] & 0xffffffffULL);  // uniform broadcast load
    const float4 zv = *reinterpret_cast<const float4*>(z + (size_t)row * DDIM + lane * 4);
    const float4 ev = *reinterpret_cast<const float4*>(embed + (size_t)k * DDIM + lane * 4);
    float4 zq;
    zq.x = zv.x + (ev.x - zv.x);
    zq.y = zv.y + (ev.y - zv.y);
    zq.z = zv.z + (ev.z - zv.z);
    zq.w = zv.w + (ev.w - zv.w);
    *reinterpret_cast<float4*>(out + OFF_ZQ + (size_t)row * DDIM + lane * 4) = zq;
    const float dx = ev.x - zv.x, dy = ev.y - zv.y, dz = ev.z - zv.z, dw = ev.w - zv.w;
    lsum += dx * dx + dy * dy + dz * dz + dw * dw;
    if (lane == 0) {
      bidx[row] = (unsigned short)k;
      out[OFF_IDX + row] = (float)k;
      atomicAdd(&hist[k], 1);
    }
  }
  #pragma unroll
  for (int off = 32; off; off >>= 1) lsum += __shfl_xor(lsum, off, 64);
  if (lane == 0) atomicAdd(loss_acc, (double)lsum);
}

// ---------------- K3: prefix scan of hist + new_cluster_size + tot + loss ----
__global__ __launch_bounds__(1024) void prefix_ncs(
    const float* __restrict__ cluster_size, const int* __restrict__ hist,
    int* __restrict__ offs, float* __restrict__ out,
    const double* __restrict__ loss_acc, float* __restrict__ tot_p) {
  __shared__ int wpart[16];
  __shared__ float fpart[16];
  const int t = threadIdx.x;
  const int lane = t & 63;
  const int wid = t >> 6;
  const int k0 = t * 4;
  int h[4];
  #pragma unroll
  for (int i = 0; i < 4; ++i) h[i] = hist[k0 + i];
  const int s = h[0] + h[1] + h[2] + h[3];
  int incl = s;
  #pragma unroll
  for (int off = 1; off < 64; off <<= 1) {
    const int v = __shfl_up(incl, off, 64);
    if (lane >= off) incl += v;
  }
  if (lane == 63) wpart[wid] = incl;
  float totl = 0.0f;
  #pragma unroll
  for (int i = 0; i < 4; ++i) {
    const float ncs = cluster_size[k0 + i] * DECAY + OMD * (float)h[i];
    out[OFF_NCS + k0 + i] = ncs;
    totl += ncs;
  }
  #pragma unroll
  for (int off = 32; off; off >>= 1) totl += __shfl_xor(totl, off, 64);
  if (lane == 0) fpart[wid] = totl;
  __syncthreads();
  int base = 0;
  for (int i = 0; i < wid; ++i) base += wpart[i];
  const int excl = base + incl - s;
  offs[k0] = excl;
  offs[k0 + 1] = excl + h[0];
  offs[k0 + 2] = excl + h[0] + h[1];
  offs[k0 + 3] = excl + h[0] + h[1] + h[2];
  if (t == 0) {
    float tt = 0.0f;
    #pragma unroll
    for (int i = 0; i < 16; ++i) tt += fpart[i];
    tot_p[0] = tt;
    out[OFF_LOSS] = (float)(2.0 * loss_acc[0] / 16777216.0);
  }
}

// ---------------- K4: scatter row ids into cluster-sorted order --------------
__global__ __launch_bounds__(256) void scatter_rows(
    const unsigned short* __restrict__ bidx, int* __restrict__ offs,
    unsigned short* __restrict__ sorted) {
  const int row = blockIdx.x * 256 + threadIdx.x;
  const int k = (int)bidx[row];
  const int pos = atomicAdd(&offs[k], 1);
  sorted[pos] = (unsigned short)row;
}

// ---------------- K5: per-cluster sum + EMA + new_embed (fused) --------------
__global__ __launch_bounds__(64) void cluster_sum(
    const float* __restrict__ z, const float* __restrict__ embed_avg,
    const unsigned short* __restrict__ sorted, const int* __restrict__ hist,
    const int* __restrict__ offs, const float* __restrict__ tot_p,
    float* __restrict__ out) {
  const int c = blockIdx.x;
  const int lane = threadIdx.x;
  const int cnt = hist[c];
  const int start = offs[c] - cnt;  // offs became end-pointers after K4
  f32x4 a0 = f32x4{0.f, 0.f, 0.f, 0.f}, a1 = a0, a2 = a0, a3 = a0;
  for (int b = 0; b < cnt; b += 64) {
    const int nn = min(64, cnt - b);
    const int myrow = (lane < nn) ? (int)sorted[start + b + lane] : 0;
    int j = 0;
    for (; j + 4 <= nn; j += 4) {
      const int r0 = __shfl(myrow, j, 64);
      const int r1 = __shfl(myrow, j + 1, 64);
      const int r2 = __shfl(myrow, j + 2, 64);
      const int r3 = __shfl(myrow, j + 3, 64);
      a0 += *reinterpret_cast<const f32x4*>(z + (size_t)r0 * DDIM + lane * 4);
      a1 += *reinterpret_cast<const f32x4*>(z + (size_t)r1 * DDIM + lane * 4);
      a2 += *reinterpret_cast<const f32x4*>(z + (size_t)r2 * DDIM + lane * 4);
      a3 += *reinterpret_cast<const f32x4*>(z + (size_t)r3 * DDIM + lane * 4);
    }
    for (; j < nn; ++j) {
      const int r0 = __shfl(myrow, j, 64);
      a0 += *reinterpret_cast<const f32x4*>(z + (size_t)r0 * DDIM + lane * 4);
    }
  }
  const f32x4 es = (a0 + a1) + (a2 + a3);
  const float tot = tot_p[0];
  const float ncs = out[OFF_NCS + c];
  const float csn = (ncs + EPSC) / (tot + (float)KCLUST * EPSC) * tot;
  const f32x4 ea = *reinterpret_cast<const f32x4*>(embed_avg + (size_t)c * DDIM + lane * 4);
  f32x4 nea, ne;
  #pragma unroll
  for (int i = 0; i < 4; ++i) {
    nea[i] = ea[i] * DECAY + OMD * es[i];
    ne[i] = nea[i] / csn;
  }
  *reinterpret_cast<f32x4*>(out + OFF_NEA + (size_t)c * DDIM + lane * 4) = nea;
  *reinterpret_cast<f32x4*>(out + OFF_NE + (size_t)c * DDIM + lane * 4) = ne;
}

extern "C" void kernel_launch(void* const* d_in, const int* in_sizes, int n_in,
                              void* d_out, int out_size, void* d_ws, size_t ws_size,
                              hipStream_t stream) {
  const float* z = (const float*)d_in[0];
  const float* embed = (const float*)d_in[1];
  const float* cluster_size = (const float*)d_in[2];
  const float* embed_avg = (const float*)d_in[3];
  float* out = (float*)d_out;
  char* wsb = (char*)d_ws;
  double* loss_acc = (double*)wsb;
  float* tot_p = (float*)(wsb + 8);
  int* hist = (int*)(wsb + WSB_HIST);
  int* offs = (int*)(wsb + WSB_OFFS);
  float* enorm = (float*)(wsb + WSB_ENORM);
  unsigned short* bidx = (unsigned short*)(wsb + WSB_BIDX);
  unsigned long long* best = (unsigned long long*)(wsb + WSB_BEST);
  unsigned short* sorted = (unsigned short*)(wsb + WSB_BEST);  // overlays best
  _Float16* eh = (_Float16*)(wsb + WSB_EH);
  _Float16* el = (_Float16*)(wsb + WSB_EL);

  hipMemsetAsync(wsb, 0, 16448, stream);                     // loss, tot, hist
  hipMemsetAsync(best, 0xFF, (size_t)BN_TOTAL * 8, stream);  // argmin keys

  presplit_embed<<<KCLUST / 4, 256, 0, stream>>>(embed, eh, el, enorm);
  dist_argmin<<<dim3(BN_TOTAL / 256, 2), 512, 0, stream>>>(z, eh, el, enorm, best);
  post_assign<<<BN_TOTAL / 16, 256, 0, stream>>>(z, embed, best, bidx, out, hist, loss_acc);
  prefix_ncs<<<1, 1024, 0, stream>>>(cluster_size, hist, offs, out, loss_acc, tot_p);
  scatter_rows<<<BN_TOTAL / 256, 256, 0, stream>>>(bidx, offs, sorted);
  cluster_sum<<<KCLUST, 64, 0, stream>>>(z, embed_avg, sorted, hist, offs, tot_p, out);
}

// Round 6
// 505.686 us; speedup vs baseline: 3.2995x; 1.3873x over previous
//
#include <hip/hip_runtime.h>
#include <stdint.h>

// Problem constants
#define BN_TOTAL 65536      // B*N = 16*4096 rows
#define DDIM 256            // D
#define KCLUST 4096         // K
#define DECAY 0.99f
#define OMD 0.01f           // 1 - DECAY
#define EPSC 1e-5f

// Output layout (float offsets into d_out), reference tuple order
#define OFF_ZQ   0
#define OFF_IDX  16777216
#define OFF_LOSS 16842752
#define OFF_NE   16842753
#define OFF_NCS  17891329
#define OFF_NEA  17895425

// ws layout (byte offsets):
//  0        loss accumulator (double, zeroed)
//  8        tot (float)
//  64       hist int[4096] (zeroed)
//  16448    offs int[4096]
//  32832    enorm f32[4096]
//  49216    bidx u16[65536]
//  180288   sorted u16[65536]
//  704576   eh fp16[4096*256]
//  2801728  el fp16[4096*256] (scaled x4096)
#define WSB_HIST   64
#define WSB_OFFS   16448
#define WSB_ENORM  32832
#define WSB_BIDX   49216
#define WSB_SORT   180288
#define WSB_EH     704576
#define WSB_EL     2801728

typedef _Float16 half8 __attribute__((ext_vector_type(8)));
typedef _Float16 half4 __attribute__((ext_vector_type(4)));
typedef float f32x4 __attribute__((ext_vector_type(4)));

#define MFMA16x32(a, b, c) __builtin_amdgcn_mfma_f32_16x16x32_f16(a, b, c, 0, 0, 0)
#define WAITVM(N) asm volatile("s_waitcnt vmcnt(" #N ")" ::: "memory")
#define WAITLGKM0 asm volatile("s_waitcnt lgkmcnt(0)" ::: "memory")

__device__ __forceinline__ void gload16(const void* gsrc, void* ldst) {
  __builtin_amdgcn_global_load_lds(
      (const __attribute__((address_space(1))) uint32_t*)(uintptr_t)gsrc,
      (__attribute__((address_space(3))) uint32_t*)(uint32_t)(uintptr_t)ldst,
      16, 0, 0);
}

// ---------------- K0: split embed -> fp16 hi/lo (+ row norms) ----------------
__global__ __launch_bounds__(256) void presplit_embed(
    const float* __restrict__ embed, _Float16* __restrict__ eh,
    _Float16* __restrict__ el, float* __restrict__ enorm) {
  const int w = threadIdx.x >> 6;
  const int l = threadIdx.x & 63;
  const int row = blockIdx.x * 4 + w;
  const f32x4 v = *reinterpret_cast<const f32x4*>(embed + (size_t)row * DDIM + l * 4);
  half4 h, lo;
  float s = 0.0f;
  #pragma unroll
  for (int j = 0; j < 4; ++j) {
    const float x = v[j];
    s += x * x;
    const _Float16 hh = (_Float16)x;
    h[j] = hh;
    lo[j] = (_Float16)((x - (float)hh) * 4096.0f);
  }
  *reinterpret_cast<half4*>(eh + (size_t)row * DDIM + l * 4) = h;
  *reinterpret_cast<half4*>(el + (size_t)row * DDIM + l * 4) = lo;
  #pragma unroll
  for (int off = 32; off; off >>= 1) s += __shfl_xor(s, off, 64);
  if (l == 0) enorm[row] = s;
}

// ---------------- K1: MFMA distance + argmin + fused epilogue ----------------
// 256 thr = 4 waves x 32 rows = 128 rows/block; full 4096-cluster sweep so the
// winner is block-local (no atomics, no `best` buffer). Double-buffered 16-col
// tiles; STAGE issued BEFORE the barrier with counted s_waitcnt vmcnt(4)
// (never 0 in-loop) so prefetch stays in flight across the barrier (T4).
// enorm lives in LDS so stage-gloads are the ONLY in-loop vm ops.
// Epilogue: loss row-term = minv + ||z||^2 (score = ||e||^2 - 2 z.e), plus
// bidx/idx/hist -- kills the post_assign kernel and its 64MB z re-read.
__global__ __launch_bounds__(256) void dist_argmin(
    const float* __restrict__ z, const _Float16* __restrict__ eh,
    const _Float16* __restrict__ el, const float* __restrict__ enormg,
    unsigned short* __restrict__ bidx, float* __restrict__ idx_out,
    int* __restrict__ hist, double* __restrict__ loss_acc) {
  __shared__ _Float16 lbuf[2][8192];   // 2 x (hi 8KB | lo 8KB) = 32KB
  __shared__ float lenorm[KCLUST];     // 16KB
  const int t = threadIdx.x;
  const int w = t >> 6;
  const int l = t & 63;
  const int lg = l >> 4;   // 0..3
  const int lr = l & 15;   // A-row / B-col / D-col
  const int m0 = blockIdx.x * 128 + w * 32;

  // ---- load z A-fragments, split f32 -> fp16 hi + scaled lo; exact ||z||^2 --
  half8 ah[2][8], al[2][8];
  float znorm[2] = {0.0f, 0.0f};
  #pragma unroll
  for (int rg = 0; rg < 2; ++rg) {
    #pragma unroll
    for (int kf = 0; kf < 8; ++kf) {
      const float* zp = z + (size_t)(m0 + rg * 16 + lr) * DDIM + kf * 32 + lg * 8;
      const f32x4 z0 = *reinterpret_cast<const f32x4*>(zp);
      const f32x4 z1 = *reinterpret_cast<const f32x4*>(zp + 4);
      #pragma unroll
      for (int j = 0; j < 4; ++j) {
        znorm[rg] += z0[j] * z0[j] + z1[j] * z1[j];
        const _Float16 h0 = (_Float16)z0[j];
        ah[rg][kf][j] = h0;
        al[rg][kf][j] = (_Float16)((z0[j] - (float)h0) * 4096.0f);
        const _Float16 h1 = (_Float16)z1[j];
        ah[rg][kf][j + 4] = h1;
        al[rg][kf][j + 4] = (_Float16)((z1[j] - (float)h1) * 4096.0f);
      }
    }
  }
  // znorm: sum the 4 lg-lanes sharing each row (lanes differ in bits 4-5)
  #pragma unroll
  for (int rg = 0; rg < 2; ++rg) {
    znorm[rg] += __shfl_xor(znorm[rg], 16, 64);
    znorm[rg] += __shfl_xor(znorm[rg], 32, 64);
  }

  // staging src offset (XOR swizzle folded into GLOBAL address; LDS linear)
  int srcoff[2];
  #pragma unroll
  for (int c01 = 0; c01 < 2; ++c01) {
    const int q = c01 * 4096 + t * 16;
    const int row = q >> 9;
    const int cc = q & 511;
    srcoff[c01] = row * 512 + (cc ^ ((row & 7) << 4));
  }
  const char* ehb = (const char*)eh;
  const char* elb = (const char*)el;

#define STAGE(nt, bb)                                                   \
  {                                                                     \
    const int nb_ = (nt) * 8192;                                        \
    char* d_ = (char*)&lbuf[bb][0];                                     \
    gload16(ehb + nb_ + srcoff[0], d_ + t * 16);                        \
    gload16(ehb + nb_ + srcoff[1], d_ + 4096 + t * 16);                 \
    gload16(elb + nb_ + srcoff[0], d_ + 8192 + t * 16);                 \
    gload16(elb + nb_ + srcoff[1], d_ + 12288 + t * 16);                \
  }

  // prologue: enorm -> LDS (4 gloads) + first tile (4 gloads).
  // No drain needed here: loop-iter-0's vmcnt(4) leaves only STAGE(1)'s 4
  // outstanding, i.e. these 8 are complete before barrier release.
  #pragma unroll
  for (int j = 0; j < 4; ++j)
    gload16((const char*)enormg + j * 4096 + t * 16,
            (char*)lenorm + j * 4096 + t * 16);
  STAGE(0, 0);

  float minv[2][4];
  int mini[2][4];
  #pragma unroll
  for (int rg = 0; rg < 2; ++rg)
    #pragma unroll
    for (int r = 0; r < 4; ++r) { minv[rg][r] = 3.4e38f; mini[rg][r] = 0; }

  int cb = 0;
  for (int nt = 0; nt < 256; ++nt) {
    if (nt < 255) {
      STAGE(nt + 1, cb ^ 1);   // prefetch BEFORE barrier, stays in flight
      WAITVM(4);               // only newest 4 (next tile) may be outstanding
    } else {
      WAITVM(0);
    }
    __builtin_amdgcn_s_barrier();
    __builtin_amdgcn_sched_barrier(0);

    const char* bb = (const char*)&lbuf[cb][0];
    f32x4 acc_h[2], acc_xa[2], acc_xb[2];
    #pragma unroll
    for (int rg = 0; rg < 2; ++rg) {
      acc_h[rg] = f32x4{0.f, 0.f, 0.f, 0.f};
      acc_xa[rg] = f32x4{0.f, 0.f, 0.f, 0.f};
      acc_xb[rg] = f32x4{0.f, 0.f, 0.f, 0.f};
    }
    const int swv = (lr & 7) << 4;
    #pragma unroll
    for (int kf = 0; kf < 8; ++kf) {
      const int ro = lr * 512 + ((kf * 64 + lg * 16) ^ swv);
      const half8 bh = *reinterpret_cast<const half8*>(bb + ro);
      const half8 bl = *reinterpret_cast<const half8*>(bb + 8192 + ro);
      acc_h[0] = MFMA16x32(ah[0][kf], bh, acc_h[0]);
      acc_h[1] = MFMA16x32(ah[1][kf], bh, acc_h[1]);
      acc_xa[0] = MFMA16x32(al[0][kf], bh, acc_xa[0]);
      acc_xa[1] = MFMA16x32(al[1][kf], bh, acc_xa[1]);
      acc_xb[0] = MFMA16x32(ah[0][kf], bl, acc_xb[0]);
      acc_xb[1] = MFMA16x32(ah[1][kf], bl, acc_xb[1]);
    }
    const int n = nt * 16 + lr;
    const float en = lenorm[n];
    #pragma unroll
    for (int rg = 0; rg < 2; ++rg) {
      #pragma unroll
      for (int r = 0; r < 4; ++r) {
        const float s = fmaf(-2.0f, acc_h[rg][r],
                        fmaf(-2.0f / 4096.0f, acc_xa[rg][r] + acc_xb[rg][r], en));
        if (s < minv[rg][r]) { minv[rg][r] = s; mini[rg][r] = n; }
      }
    }
    WAITLGKM0;                      // this wave's LDS reads retired
    __builtin_amdgcn_s_barrier();   // all readers done -> next overwrite safe
    cb ^= 1;
  }
#undef STAGE

  // butterfly over the 16 lr lanes (cols of the same row); all lanes end with
  // the winner for row (rg, lg*4+r)
  #pragma unroll
  for (int mask = 1; mask < 16; mask <<= 1) {
    #pragma unroll
    for (int rg = 0; rg < 2; ++rg) {
      #pragma unroll
      for (int r = 0; r < 4; ++r) {
        const float ov = __shfl_xor(minv[rg][r], mask, 64);
        const int oi = __shfl_xor(mini[rg][r], mask, 64);
        if (ov < minv[rg][r] || (ov == minv[rg][r] && oi < mini[rg][r])) {
          minv[rg][r] = ov;
          mini[rg][r] = oi;
        }
      }
    }
  }

  float lsum = 0.0f;
  #pragma unroll
  for (int rg = 0; rg < 2; ++rg) {
    #pragma unroll
    for (int r = 0; r < 4; ++r) {
      const int rowl = lg * 4 + r;                       // D row within 16
      const int src = (l & 48) | rowl;                   // lane holding znorm(rowl)
      const float zn = __shfl(znorm[rg], src, 64);
      if (lr == 0) {
        const int grow = m0 + rg * 16 + rowl;
        const int k = mini[rg][r];
        bidx[grow] = (unsigned short)k;
        idx_out[grow] = (float)k;
        atomicAdd(&hist[k], 1);
        lsum += minv[rg][r] + zn;                        // = ||e-z||^2 of winner
      }
    }
  }
  #pragma unroll
  for (int off = 32; off; off >>= 1) lsum += __shfl_xor(lsum, off, 64);
  if (l == 0) atomicAdd(loss_acc, (double)lsum);
}

// ---------------- K2: z_q_st = embed[k] (pure copy) --------------------------
__global__ __launch_bounds__(256) void zq_write(
    const float* __restrict__ embed, const unsigned short* __restrict__ bidx,
    float* __restrict__ out) {
  const int w = threadIdx.x >> 6;
  const int lane = threadIdx.x & 63;
  const int base = blockIdx.x * 16 + w * 4;
  #pragma unroll
  for (int rr = 0; rr < 4; ++rr) {
    const int row = base + rr;
    const int k = (int)bidx[row];
    const f32x4 ev = *reinterpret_cast<const f32x4*>(embed + (size_t)k * DDIM + lane * 4);
    *reinterpret_cast<f32x4*>(out + OFF_ZQ + (size_t)row * DDIM + lane * 4) = ev;
  }
}

// ---------------- K3: prefix scan of hist + new_cluster_size + tot + loss ----
__global__ __launch_bounds__(1024) void prefix_ncs(
    const float* __restrict__ cluster_size, const int* __restrict__ hist,
    int* __restrict__ offs, float* __restrict__ out,
    const double* __restrict__ loss_acc, float* __restrict__ tot_p) {
  __shared__ int wpart[16];
  __shared__ float fpart[16];
  const int t = threadIdx.x;
  const int lane = t & 63;
  const int wid = t >> 6;
  const int k0 = t * 4;
  int h[4];
  #pragma unroll
  for (int i = 0; i < 4; ++i) h[i] = hist[k0 + i];
  const int s = h[0] + h[1] + h[2] + h[3];
  int incl = s;
  #pragma unroll
  for (int off = 1; off < 64; off <<= 1) {
    const int v = __shfl_up(incl, off, 64);
    if (lane >= off) incl += v;
  }
  if (lane == 63) wpart[wid] = incl;
  float totl = 0.0f;
  #pragma unroll
  for (int i = 0; i < 4; ++i) {
    const float ncs = cluster_size[k0 + i] * DECAY + OMD * (float)h[i];
    out[OFF_NCS + k0 + i] = ncs;
    totl += ncs;
  }
  #pragma unroll
  for (int off = 32; off; off >>= 1) totl += __shfl_xor(totl, off, 64);
  if (lane == 0) fpart[wid] = totl;
  __syncthreads();
  int base = 0;
  for (int i = 0; i < wid; ++i) base += wpart[i];
  const int excl = base + incl - s;
  offs[k0] = excl;
  offs[k0 + 1] = excl + h[0];
  offs[k0 + 2] = excl + h[0] + h[1];
  offs[k0 + 3] = excl + h[0] + h[1] + h[2];
  if (t == 0) {
    float tt = 0.0f;
    #pragma unroll
    for (int i = 0; i < 16; ++i) tt += fpart[i];
    tot_p[0] = tt;
    out[OFF_LOSS] = (float)(2.0 * loss_acc[0] / 16777216.0);
  }
}

// ---------------- K4: scatter row ids into cluster-sorted order --------------
__global__ __launch_bounds__(256) void scatter_rows(
    const unsigned short* __restrict__ bidx, int* __restrict__ offs,
    unsigned short* __restrict__ sorted) {
  const int row = blockIdx.x * 256 + threadIdx.x;
  const int k = (int)bidx[row];
  const int pos = atomicAdd(&offs[k], 1);
  sorted[pos] = (unsigned short)row;
}

// ---------------- K5: per-cluster sum + EMA + new_embed (fused, 4 waves) -----
__global__ __launch_bounds__(256) void cluster_sum(
    const float* __restrict__ z, const float* __restrict__ embed_avg,
    const unsigned short* __restrict__ sorted, const int* __restrict__ hist,
    const int* __restrict__ offs, const float* __restrict__ tot_p,
    float* __restrict__ out) {
  __shared__ unsigned short ids[2048];
  __shared__ f32x4 red[3][64];
  const int c = blockIdx.x;
  const int t = threadIdx.x;
  const int w = t >> 6;
  const int lane = t & 63;
  const int cnt = hist[c];
  const int start = offs[c] - cnt;  // offs became end-pointers after K4
  f32x4 acc = f32x4{0.f, 0.f, 0.f, 0.f};
  for (int ch = 0; ch < cnt; ch += 2048) {
    const int nn = min(2048, cnt - ch);
    __syncthreads();
    for (int i = t; i < nn; i += 256) ids[i] = sorted[start + ch + i];
    __syncthreads();
    for (int j = w; j < nn; j += 4) {
      const int row = (int)ids[j];
      acc += *reinterpret_cast<const f32x4*>(z + (size_t)row * DDIM + lane * 4);
    }
  }
  if (w > 0) red[w - 1][lane] = acc;
  __syncthreads();
  if (w == 0) {
    acc += red[0][lane];
    acc += red[1][lane];
    acc += red[2][lane];
    const float tot = tot_p[0];
    const float ncs = out[OFF_NCS + c];
    const float csn = (ncs + EPSC) / (tot + (float)KCLUST * EPSC) * tot;
    const f32x4 ea = *reinterpret_cast<const f32x4*>(embed_avg + (size_t)c * DDIM + lane * 4);
    f32x4 nea, ne;
    #pragma unroll
    for (int i = 0; i < 4; ++i) {
      nea[i] = ea[i] * DECAY + OMD * acc[i];
      ne[i] = nea[i] / csn;
    }
    *reinterpret_cast<f32x4*>(out + OFF_NEA + (size_t)c * DDIM + lane * 4) = nea;
    *reinterpret_cast<f32x4*>(out + OFF_NE + (size_t)c * DDIM + lane * 4) = ne;
  }
}

extern "C" void kernel_launch(void* const* d_in, const int* in_sizes, int n_in,
                              void* d_out, int out_size, void* d_ws, size_t ws_size,
                              hipStream_t stream) {
  const float* z = (const float*)d_in[0];
  const float* embed = (const float*)d_in[1];
  const float* cluster_size = (const float*)d_in[2];
  const float* embed_avg = (const float*)d_in[3];
  float* out = (float*)d_out;
  char* wsb = (char*)d_ws;
  double* loss_acc = (double*)wsb;
  float* tot_p = (float*)(wsb + 8);
  int* hist = (int*)(wsb + WSB_HIST);
  int* offs = (int*)(wsb + WSB_OFFS);
  float* enorm = (float*)(wsb + WSB_ENORM);
  unsigned short* bidx = (unsigned short*)(wsb + WSB_BIDX);
  unsigned short* sorted = (unsigned short*)(wsb + WSB_SORT);
  _Float16* eh = (_Float16*)(wsb + WSB_EH);
  _Float16* el = (_Float16*)(wsb + WSB_EL);

  hipMemsetAsync(wsb, 0, 16448, stream);  // loss, tot, hist

  presplit_embed<<<KCLUST / 4, 256, 0, stream>>>(embed, eh, el, enorm);
  dist_argmin<<<BN_TOTAL / 128, 256, 0, stream>>>(
      z, eh, el, enorm, bidx, out + OFF_IDX, hist, loss_acc);
  zq_write<<<BN_TOTAL / 16, 256, 0, stream>>>(embed, bidx, out);
  prefix_ncs<<<1, 1024, 0, stream>>>(cluster_size, hist, offs, out, loss_acc, tot_p);
  scatter_rows<<<BN_TOTAL / 256, 256, 0, stream>>>(bidx, offs, sorted);
  cluster_sum<<<KCLUST, 256, 0, stream>>>(z, embed_avg, sorted, hist, offs, tot_p, out);
}